// Round 4
// baseline (5068.509 us; speedup 1.0000x reference)
//
#include <hip/hip_runtime.h>

typedef _Float16 f16;
typedef _Float16 f16x4 __attribute__((ext_vector_type(4)));
typedef _Float16 f16x8 __attribute__((ext_vector_type(8)));
typedef float f32x4 __attribute__((ext_vector_type(4)));
typedef int i32x2 __attribute__((ext_vector_type(2)));

#define S_LEN 512
#define BSZ 64
#define ISZ 512
#define HSZ 1024

__device__ __forceinline__ float fast_sigmoid(float x) {
  return 1.f / (1.f + __expf(-x));
}
__device__ __forceinline__ float fast_tanh(float x) {
  float t = __expf(-2.f * fabsf(x));
  float r = (1.f - t) / (1.f + t);
  return copysignf(r, x);
}

// device-coherent (sc1 = served at the coherence point) accessors
__device__ __forceinline__ void st16_sc1(f16* p, f16x8 v) {
  asm volatile("global_store_dwordx4 %0, %1, off sc1" :: "v"(p), "v"(v) : "memory");
}
__device__ __forceinline__ int ld_flag_sc1(const int* p) {
  int v;
  asm volatile("global_load_dword %0, %1, off sc1\n\ts_waitcnt vmcnt(0)"
               : "=v"(v) : "v"(p) : "memory");
  return v;
}
__device__ __forceinline__ void st_flag_sc1(int* p, int v) {
  asm volatile("global_store_dword %0, %1, off sc1" :: "v"(p), "v"(v) : "memory");
}
// 4 A-fragment loads (sc1) + gx prefetch in one bundle; waits only the A-loads
// (vmcnt(1): in-order, so all 4 A done, gx still in flight). Outputs are
// EARLY-CLOBBER: they must not alias the address regs %5/%6, which are read
// at issue of LATER loads in the same bundle.
__device__ __forceinline__ void ld_afrags(f16x8& a0, f16x8& a1, f16x8& a2, f16x8& a3,
                                          i32x2& gx, const f16* ap, const f16* gp) {
  asm volatile(
    "global_load_dwordx4 %0, %5, off sc1\n\t"
    "global_load_dwordx4 %1, %5, off offset:512 sc1\n\t"
    "global_load_dwordx4 %2, %5, off offset:1024 sc1\n\t"
    "global_load_dwordx4 %3, %5, off offset:1536 sc1\n\t"
    "global_load_dwordx2 %4, %6, off\n\t"
    "s_waitcnt vmcnt(1)"
    : "=&v"(a0), "=&v"(a1), "=&v"(a2), "=&v"(a3), "=&v"(gx)
    : "v"(ap), "v"(gp) : "memory");
}

// ---- setup kernels -------------------------------------------------------
__global__ void k_cvt(const float* __restrict__ src, f16* __restrict__ dst, int n4) {
  int i = blockIdx.x * blockDim.x + threadIdx.x;
  if (i < n4) {
    float4 v = ((const float4*)src)[i];
    f16x4 h = { (f16)v.x, (f16)v.y, (f16)v.z, (f16)v.w };
    ((f16x4*)dst)[i] = h;
  }
}

// packed row P = w*128 + v*16 + u*4 + cls  <->  orig row = cls*1024 + (w*32 + v*4 + u)
__global__ void k_pack_whh(const float* __restrict__ whh, f16* __restrict__ wp) {
  int i = blockIdx.x * blockDim.x + threadIdx.x;
  int idx4 = i * 4;
  int k = idx4 & (HSZ - 1);
  int P = idx4 >> 10;
  int cls = P & 3, u = (P >> 2) & 3, v = (P >> 4) & 7, w = P >> 7;
  int srow = cls * HSZ + w * 32 + v * 4 + u;
  float4 val = *(const float4*)&whh[(size_t)srow * HSZ + k];
  f16x4 h = { (f16)val.x, (f16)val.y, (f16)val.z, (f16)val.w };
  *(f16x4*)&wp[(size_t)P * HSZ + k] = h;
}

__global__ void k_misc(const float* __restrict__ bih, const float* __restrict__ bhh,
                       float* __restrict__ bsum, f16* __restrict__ hbuf,
                       int* __restrict__ bar) {
  int i = blockIdx.x * blockDim.x + threadIdx.x;
  if (i < 4096) bsum[i] = bih[i] + bhh[i];
  if (i < BSZ * HSZ) hbuf[i] = (f16)0.f;   // zero h ping buffer 0 (ws is poisoned)
  if (i < 1024) bar[i] = 0;                // per-WG publish flags
}

// ---- phase 1: gx = x @ w_ih^T + (b_ih + b_hh) ----------------------------
// output layout: [s][g(8)][w(32)][v(8)][b(8)][u(4)][cls(4)] f16
__global__ __launch_bounds__(256) void k_gemm_gx(
    const f16* __restrict__ xh, const f16* __restrict__ wh,
    const float* __restrict__ bsum, f16* __restrict__ gxp)
{
  __shared__ f16 As[128][40];
  __shared__ f16 Bs[128][40];
  const int bn = blockIdx.x, bm = blockIdx.y;
  const int tid = threadIdx.x;
  const int wid = tid >> 6, lane = tid & 63;
  const int wy = wid >> 1, wx = wid & 1;
  const int l15 = lane & 15, lq = lane >> 4;
  const int sr = tid >> 2, sc = (tid & 3) * 8;
  f32x4 acc[4][4] = {};
  const size_t arow = (size_t)bm * 128;
  const size_t brow = (size_t)bn * 128;
  for (int k0 = 0; k0 < ISZ; k0 += 32) {
    __syncthreads();
    *(f16x8*)&As[sr][sc]      = *(const f16x8*)&xh[(arow + sr) * ISZ + k0 + sc];
    *(f16x8*)&As[sr + 64][sc] = *(const f16x8*)&xh[(arow + sr + 64) * ISZ + k0 + sc];
    *(f16x8*)&Bs[sr][sc]      = *(const f16x8*)&wh[(brow + sr) * ISZ + k0 + sc];
    *(f16x8*)&Bs[sr + 64][sc] = *(const f16x8*)&wh[(brow + sr + 64) * ISZ + k0 + sc];
    __syncthreads();
    f16x8 af[4], bf[4];
    #pragma unroll
    for (int t = 0; t < 4; t++) af[t] = *(const f16x8*)&As[wy * 64 + t * 16 + l15][lq * 8];
    #pragma unroll
    for (int t = 0; t < 4; t++) bf[t] = *(const f16x8*)&Bs[wx * 64 + t * 16 + l15][lq * 8];
    #pragma unroll
    for (int mt = 0; mt < 4; mt++)
      #pragma unroll
      for (int nt = 0; nt < 4; nt++)
        acc[mt][nt] = __builtin_amdgcn_mfma_f32_16x16x32_f16(af[mt], bf[nt], acc[mt][nt], 0, 0, 0);
  }
  #pragma unroll
  for (int nt = 0; nt < 4; nt++) {
    const int n = bn * 128 + wx * 64 + nt * 16 + l15;
    const float bs = bsum[n];
    const int cls = n >> 10, j = n & 1023;
    const int w = j >> 5, v = (j >> 2) & 7, u = j & 3;
    #pragma unroll
    for (int mt = 0; mt < 4; mt++) {
      const int m0 = bm * 128 + wy * 64 + mt * 16 + lq * 4;
      #pragma unroll
      for (int r = 0; r < 4; r++) {
        const int m = m0 + r;
        const int b = m >> 9, s = m & 511;
        const int g = b >> 3, bl = b & 7;
        gxp[(((size_t)s * 8 + g) * 32 + w) * 1024 + v * 128 + bl * 16 + u * 4 + cls]
            = (f16)(acc[mt][nt][r] + bs);
      }
    }
  }
}

// ---- phase 2: persistent recurrence, 8 independent batch groups ----------
// 256 WGs x 512 thr. Group g = wg&7 (batches 8g..8g+7), WG w = wg>>3 owns
// units [32w,32w+32) (128 packed gate rows = N). K-SPLIT across waves:
// wave wid holds weights for ALL 128 rows x K-chunk [wid*128,+128) (128 VGPR,
// pinned resident via per-iteration keep-alive asm) and polls exactly the 4
// producers covering that K-chunk. A-fragments load DIRECTLY from published
// hbuf (global->VGPR, fragment-shaped layout) -- no LDS h staging, no WG-wide
// wait before MFMA. 8-way cross-wave reduce of partial gates via pre[] LDS.
// hbuf layout: [p][g][w'][b(8)][u(32)] f16.
__global__ __launch_bounds__(512, 2) void k_lstm(
    const f16* __restrict__ wp, const f16* __restrict__ gxp,
    f16* __restrict__ hbuf, int* __restrict__ bar, float* __restrict__ out)
{
  __shared__ __align__(16) float pre[8][128][12];  // partial gates [v][n][b], pad 12
  __shared__ __align__(16) f16 hpub[256];          // this WG's h, [b][u] for publish
  const int wg = blockIdx.x;
  const int g  = wg & 7;
  const int w  = wg >> 3;
  const int tid = threadIdx.x;
  const int lane = tid & 63;
  const int wid = tid >> 6;
  const int l15 = lane & 15, lq = lane >> 4;
  const int hr8 = l15 & 7;
  int* flags = &bar[g * 32];

  // B-fragments (w_hh): wave wid holds ALL 128 packed rows x its K-chunk.
  // wv[nt*4+kk] = rows [w*128+nt*16,+16) x K [wid*128+kk*32,+32)
  f16x8 wv[32];
  {
    const f16* wsrc = wp + (size_t)(w * 128 + l15) * HSZ + wid * 128 + lq * 8;
    #pragma unroll
    for (int nt = 0; nt < 8; nt++)
      #pragma unroll
      for (int kk = 0; kk < 4; kk++)
        wv[nt * 4 + kk] = *(const f16x8*)(wsrc + (size_t)nt * 16 * HSZ + kk * 32);
  }

  // this wave's 4 producers: w' = wid*4 .. wid*4+3
  const int* fp = &flags[wid * 4 + (lane & 3)];
  int* myflag = &flags[w];

  const int vb = (lane >> 5) * 4;            // reduce: lanes<32 sum v 0-3, >=32 sum 4-7
  const int ee = lane & 31;
  const int eb = ee >> 2, eu = ee & 3;       // elementwise (b, unit-in-wave)
  const int n0 = wid * 16 + eu * 4;          // packed-row base for this thread
  float creg = 0.f;
  const size_t hseq = (size_t)S_LEN * BSZ * HSZ;
  int p = 0;
  for (int s = 0; s < S_LEN; s++) {
    // pin weight fragments: forces wv to stay loop-carried in VGPRs (the
    // compiler otherwise demotes them and re-loads from L2 every step)
    #pragma unroll
    for (int t = 0; t < 32; t++) asm volatile("" : "+v"(wv[t]));
    // wait until this wave's 4 producers have published step s
    for (;;) {
      int v = 0x7fffffff;
      if (lane < 4) v = ld_flag_sc1(fp);
      if (__all(v >= s)) break;
      __builtin_amdgcn_s_sleep(1);
    }
    // A-fragments straight from published h + gx prefetch (gx stays in flight)
    f16x8 a0, a1, a2, a3;
    i32x2 gxr;
    {
      const f16* ap = hbuf + ((size_t)p * 8 + g) * 8192 + (size_t)(wid * 4) * 256
                    + hr8 * 32 + lq * 8;
      const f16* gp = &gxp[(((size_t)s * 8 + g) * 32 + w) * 1024 + wid * 128 + (lane & 31) * 4];
      ld_afrags(a0, a1, a2, a3, gxr, ap, gp);
    }
    // partial gates for all 128 rows over this wave's K=128 chunk
    f32x4 acc[8] = {};
    #pragma unroll
    for (int nt = 0; nt < 8; nt++) acc[nt] = __builtin_amdgcn_mfma_f32_16x16x32_f16(a0, wv[nt * 4 + 0], acc[nt], 0, 0, 0);
    #pragma unroll
    for (int nt = 0; nt < 8; nt++) acc[nt] = __builtin_amdgcn_mfma_f32_16x16x32_f16(a1, wv[nt * 4 + 1], acc[nt], 0, 0, 0);
    #pragma unroll
    for (int nt = 0; nt < 8; nt++) acc[nt] = __builtin_amdgcn_mfma_f32_16x16x32_f16(a2, wv[nt * 4 + 2], acc[nt], 0, 0, 0);
    #pragma unroll
    for (int nt = 0; nt < 8; nt++) acc[nt] = __builtin_amdgcn_mfma_f32_16x16x32_f16(a3, wv[nt * 4 + 3], acc[nt], 0, 0, 0);
    // write partials: C layout col(n)=l15, rows(b)=lq*4+r (lq>=2 dup of <2)
    if (lq < 2)
      #pragma unroll
      for (int nt = 0; nt < 8; nt++)
        *(f32x4*)&pre[wid][nt * 16 + l15][lq * 4] = acc[nt];
    asm volatile("s_waitcnt lgkmcnt(0)\n\ts_barrier" ::: "memory");   // bar1
    // gx ready; "+v" ties gxr's USES to after this wait (reg-only ops aren't
    // ordered by the "memory" clobber alone)
    asm volatile("s_waitcnt vmcnt(0)" : "+v"(gxr) :: "memory");
    const f16x4 gxv = __builtin_bit_cast(f16x4, gxr);
    // 8-way reduce: each half sums 4 waves' partials, then cross-half shuffle
    float q0 = 0.f, q1 = 0.f, q2 = 0.f, q3 = 0.f;
    #pragma unroll
    for (int vi = 0; vi < 4; vi++) {
      q0 += pre[vb + vi][n0 + 0][eb];
      q1 += pre[vb + vi][n0 + 1][eb];
      q2 += pre[vb + vi][n0 + 2][eb];
      q3 += pre[vb + vi][n0 + 3][eb];
    }
    q0 += __shfl_xor(q0, 32);
    q1 += __shfl_xor(q1, 32);
    q2 += __shfl_xor(q2, 32);
    q3 += __shfl_xor(q3, 32);
    if (lane < 32) {
      const float ig = fast_sigmoid(q0 + (float)gxv[0]);
      const float fg = fast_sigmoid(q1 + (float)gxv[1]);
      const float gg = fast_tanh(q2 + (float)gxv[2]);
      const float og = fast_sigmoid(q3 + (float)gxv[3]);
      creg = fg * creg + ig * gg;
      const float h = og * fast_tanh(creg);
      hpub[eb * 32 + wid * 4 + eu] = (f16)h;
      // out store: normal cached, fire-and-forget (barriers are lgkm-only)
      out[((size_t)s * BSZ + g * 8 + eb) * HSZ + w * 32 + wid * 4 + eu] = h;
      if (s == S_LEN - 1) {
        const int b = g * 8 + eb, J = w * 32 + wid * 4 + eu;
        out[hseq + (size_t)b * HSZ + J] = h;                          // h_f
        out[hseq + (size_t)BSZ * HSZ + (size_t)b * HSZ + J] = creg;   // c_f
      }
    }
    asm volatile("s_waitcnt lgkmcnt(0)\n\ts_barrier" ::: "memory");   // bar2
    // publish: wave 0 gathers hpub, ONE contiguous 512B sc1 store, drain, flag
    if (wid == 0 && s + 1 < S_LEN) {
      if (lane < 32) {
        f16x8 hv = *(const f16x8*)&hpub[lane * 8];
        st16_sc1(&hbuf[((size_t)(p ^ 1) * 8 + g) * 8192 + w * 256 + lane * 8], hv);
      }
      asm volatile("s_waitcnt vmcnt(0)" ::: "memory");
      if (lane == 0) st_flag_sc1(myflag, s + 1);
    }
    p ^= 1;
  }
}

// ---- launch --------------------------------------------------------------
extern "C" void kernel_launch(void* const* d_in, const int* in_sizes, int n_in,
                              void* d_out, int out_size, void* d_ws, size_t ws_size,
                              hipStream_t stream) {
  const float* x   = (const float*)d_in[0];
  const float* wih = (const float*)d_in[1];
  const float* whh = (const float*)d_in[2];
  const float* bih = (const float*)d_in[3];
  const float* bhh = (const float*)d_in[4];
  float* out = (float*)d_out;
  char* ws = (char*)d_ws;
  f16*   xh    = (f16*)(ws + 0);           // 33,554,432
  f16*   wih_h = (f16*)(ws + 33554432);    //  4,194,304
  f16*   wp    = (f16*)(ws + 37748736);    //  8,388,608
  float* bsum  = (float*)(ws + 46137344);  //     16,384
  f16*   hbuf  = (f16*)(ws + 46153728);    //    262,144
  f16*   gxp   = (f16*)(ws + 46415872);    // 268,435,456
  int*   bar   = (int*)(ws + 314851328);   //      4,096
  // total 314,855,424 B

  k_cvt<<<16384, 256, 0, stream>>>(x, xh, (BSZ * S_LEN * ISZ) / 4);
  k_cvt<<<2048, 256, 0, stream>>>(wih, wih_h, (4 * HSZ * ISZ) / 4);
  k_pack_whh<<<4096, 256, 0, stream>>>(whh, wp);
  k_misc<<<256, 256, 0, stream>>>(bih, bhh, bsum, hbuf, bar);
  dim3 g1(32, 256);
  k_gemm_gx<<<g1, 256, 0, stream>>>(xh, wih_h, bsum, gxp);
  void* args[] = { (void*)&wp, (void*)&gxp, (void*)&hbuf, (void*)&bar, (void*)&out };
  hipLaunchCooperativeKernel((void*)k_lstm, dim3(256), dim3(512), args, 0, stream);
}

// Round 5
// 2318.900 us; speedup vs baseline: 2.1857x; 2.1857x over previous
//
#include <hip/hip_runtime.h>

typedef _Float16 f16;
typedef _Float16 f16x4 __attribute__((ext_vector_type(4)));
typedef _Float16 f16x8 __attribute__((ext_vector_type(8)));
typedef float f32x4 __attribute__((ext_vector_type(4)));
typedef int i32x4 __attribute__((ext_vector_type(4)));
typedef unsigned short ushort4v __attribute__((ext_vector_type(4)));

#define S_LEN 512
#define BSZ 64
#define ISZ 512
#define HSZ 1024

__device__ __forceinline__ float fast_sigmoid(float x) {
  return 1.f / (1.f + __expf(-x));
}
__device__ __forceinline__ float fast_tanh(float x) {
  float t = __expf(-2.f * fabsf(x));
  float r = (1.f - t) / (1.f + t);
  return copysignf(r, x);
}

// device-coherent (sc1 = served at the coherence point) 16B store
__device__ __forceinline__ void st16_sc1(f16* p, f16x8 v) {
  asm volatile("global_store_dwordx4 %0, %1, off sc1" :: "v"(p), "v"(v) : "memory");
}
// paired 16B sc1 loads + full drain (the poll/stage load)
__device__ __forceinline__ void ld2x16_sc1(f16x8& d0, f16x8& d1,
                                           const f16* p0, const f16* p1) {
  asm volatile(
    "global_load_dwordx4 %0, %2, off sc1\n\t"
    "global_load_dwordx4 %1, %3, off sc1\n\t"
    "s_waitcnt vmcnt(0)"
    : "=&v"(d0), "=&v"(d1) : "v"(p0), "v"(p1) : "memory");
}

// ---- setup kernels -------------------------------------------------------
__global__ void k_cvt(const float* __restrict__ src, f16* __restrict__ dst, int n4) {
  int i = blockIdx.x * blockDim.x + threadIdx.x;
  if (i < n4) {
    float4 v = ((const float4*)src)[i];
    f16x4 h = { (f16)v.x, (f16)v.y, (f16)v.z, (f16)v.w };
    ((f16x4*)dst)[i] = h;
  }
}

// packed row P = w*128 + v*16 + u*4 + cls  <->  orig row = cls*1024 + (w*32 + v*4 + u)
__global__ void k_pack_whh(const float* __restrict__ whh, f16* __restrict__ wp) {
  int i = blockIdx.x * blockDim.x + threadIdx.x;
  int idx4 = i * 4;
  int k = idx4 & (HSZ - 1);
  int P = idx4 >> 10;
  int cls = P & 3, u = (P >> 2) & 3, v = (P >> 4) & 7, w = P >> 7;
  int srow = cls * HSZ + w * 32 + v * 4 + u;
  float4 val = *(const float4*)&whh[(size_t)srow * HSZ + k];
  f16x4 h = { (f16)val.x, (f16)val.y, (f16)val.z, (f16)val.w };
  *(f16x4*)&wp[(size_t)P * HSZ + k] = h;
}

// bsum = b_ih + b_hh; hbuf: 4 step-slots x 8 groups x 8192 f16.
// Slot 0 = 0.0 (initial h); slots 1-3 = sentinel 0xFFFF (-NaN, never produced
// by finite math). 65,536 threads x 4 f16 covers all 262,144 f16.
__global__ void k_misc(const float* __restrict__ bih, const float* __restrict__ bhh,
                       float* __restrict__ bsum, f16* __restrict__ hbuf) {
  int i = blockIdx.x * blockDim.x + threadIdx.x;
  if (i < 4096) bsum[i] = bih[i] + bhh[i];
  unsigned short v = (i >= 16384) ? 0xFFFFu : 0u;   // slot = (i*4)>>16
  ushort4v q = { v, v, v, v };
  ((ushort4v*)hbuf)[i] = q;
}

// ---- phase 1: gx = x @ w_ih^T + (b_ih + b_hh) ----------------------------
// output layout: [s][g(8)][w(32)][v(8)][b(8)][u(4)][cls(4)] f16
__global__ __launch_bounds__(256) void k_gemm_gx(
    const f16* __restrict__ xh, const f16* __restrict__ wh,
    const float* __restrict__ bsum, f16* __restrict__ gxp)
{
  __shared__ f16 As[128][40];
  __shared__ f16 Bs[128][40];
  const int bn = blockIdx.x, bm = blockIdx.y;
  const int tid = threadIdx.x;
  const int wid = tid >> 6, lane = tid & 63;
  const int wy = wid >> 1, wx = wid & 1;
  const int l15 = lane & 15, lq = lane >> 4;
  const int sr = tid >> 2, sc = (tid & 3) * 8;
  f32x4 acc[4][4] = {};
  const size_t arow = (size_t)bm * 128;
  const size_t brow = (size_t)bn * 128;
  for (int k0 = 0; k0 < ISZ; k0 += 32) {
    __syncthreads();
    *(f16x8*)&As[sr][sc]      = *(const f16x8*)&xh[(arow + sr) * ISZ + k0 + sc];
    *(f16x8*)&As[sr + 64][sc] = *(const f16x8*)&xh[(arow + sr + 64) * ISZ + k0 + sc];
    *(f16x8*)&Bs[sr][sc]      = *(const f16x8*)&wh[(brow + sr) * ISZ + k0 + sc];
    *(f16x8*)&Bs[sr + 64][sc] = *(const f16x8*)&wh[(brow + sr + 64) * ISZ + k0 + sc];
    __syncthreads();
    f16x8 af[4], bf[4];
    #pragma unroll
    for (int t = 0; t < 4; t++) af[t] = *(const f16x8*)&As[wy * 64 + t * 16 + l15][lq * 8];
    #pragma unroll
    for (int t = 0; t < 4; t++) bf[t] = *(const f16x8*)&Bs[wx * 64 + t * 16 + l15][lq * 8];
    #pragma unroll
    for (int mt = 0; mt < 4; mt++)
      #pragma unroll
      for (int nt = 0; nt < 4; nt++)
        acc[mt][nt] = __builtin_amdgcn_mfma_f32_16x16x32_f16(af[mt], bf[nt], acc[mt][nt], 0, 0, 0);
  }
  #pragma unroll
  for (int nt = 0; nt < 4; nt++) {
    const int n = bn * 128 + wx * 64 + nt * 16 + l15;
    const float bs = bsum[n];
    const int cls = n >> 10, j = n & 1023;
    const int w = j >> 5, v = (j >> 2) & 7, u = j & 3;
    #pragma unroll
    for (int mt = 0; mt < 4; mt++) {
      const int m0 = bm * 128 + wy * 64 + mt * 16 + lq * 4;
      #pragma unroll
      for (int r = 0; r < 4; r++) {
        const int m = m0 + r;
        const int b = m >> 9, s = m & 511;
        const int g = b >> 3, bl = b & 7;
        gxp[(((size_t)s * 8 + g) * 32 + w) * 1024 + v * 128 + bl * 16 + u * 4 + cls]
            = (f16)(acc[mt][nt][r] + bs);
      }
    }
  }
}

// ---- phase 2: persistent recurrence, 8 independent batch groups ----------
// 256 WGs x 512 thr (R2 N-split structure). Group g = wg&7 (batches 8g..8g+7),
// WG w = wg>>3 owns units [32w,32w+32). Wave wid owns 16 packed rows x full
// K=1024 (weights stream from L2; no cross-wave reduce -- wave-local LDS
// transpose bounce only).
// h exchange is DATA-AS-FLAG: 4 rotating step-slot buffers; consumers poll
// the data itself (dword != 0xFFFFFFFF sentinel check; dword visibility is
// atomic and each dword is both-sentinel or both-real). Publish is a single
// fire-and-forget 512B sc1 store (no drain, no flag). Slot recycling: each WG
// re-sentinels its own 512B chunk of slot (s-1) after barB; wave 7 drains the
// reset before barA, so the WG's own publish (after barA) happens-before any
// consumer that could later poll the recycled slot.
// hbuf layout: [slot(4)][g(8)][w'(32)][b(8)][u(32)] f16.
__global__ __launch_bounds__(512, 2) void k_lstm(
    const f16* __restrict__ wp, const f16* __restrict__ gxp,
    f16* __restrict__ hbuf, float* __restrict__ out)
{
  __shared__ __align__(16) f16 hs[8192];          // staged group h, [w'][b][u] linear
  __shared__ __align__(16) float pre[8][16][12];  // per-wave gate pre-acts [n][b]
  __shared__ __align__(16) f16 hpub[256];         // this WG's h, [b][u] for publish
  const int wg = blockIdx.x;
  const int g  = wg & 7;
  const int w  = wg >> 3;
  const int tid = threadIdx.x;
  const int lane = tid & 63;
  const int wid = tid >> 6;
  const int l15 = lane & 15, lq = lane >> 4;
  const int hr = l15 & 7;

  // B-fragments (w_hh): wave wid owns packed rows [w*128 + wid*16, +16),
  // full K=1024 -> 32 slices (streams from L2 each step; that's fine).
  f16x8 wv[32];
  {
    const f16* wsrc = wp + (size_t)(w * 128 + wid * 16 + l15) * HSZ + lq * 8;
    #pragma unroll
    for (int t = 0; t < 32; t++) wv[t] = *(const f16x8*)(wsrc + t * 32);
  }

  const f16x8 sentinel16 = __builtin_bit_cast(f16x8, (i32x4){-1, -1, -1, -1});
  const int eb = lane >> 2, eu = lane & 3;   // elementwise mapping (lanes<32)
  float creg = 0.f;
  const size_t hseq = (size_t)S_LEN * BSZ * HSZ;
  for (int s = 0; s < S_LEN; s++) {
    // prefetch this step's gx slice (normal cached load; drained by poll's vmcnt)
    f16x4 gxv = {};
    if (lane < 32)
      gxv = *(const f16x4*)&gxp[(((size_t)s * 8 + g) * 32 + w) * 1024
                                + wid * 128 + lane * 4];
    // poll+stage merged: load own 2x16B share of slot s; valid when no dword
    // is the sentinel (all-or-nothing per dword -> no tearing ambiguity)
    f16x8 s0v, s1v;
    {
      const f16* hsrc = hbuf + ((size_t)(s & 3) * 8 + g) * 8192 + (size_t)tid * 8;
      for (;;) {
        ld2x16_sc1(s0v, s1v, hsrc, hsrc + 4096);
        i32x4 u0 = __builtin_bit_cast(i32x4, s0v);
        i32x4 u1 = __builtin_bit_cast(i32x4, s1v);
        bool ok = (u0[0] != -1) && (u0[1] != -1) && (u0[2] != -1) && (u0[3] != -1)
               && (u1[0] != -1) && (u1[1] != -1) && (u1[2] != -1) && (u1[3] != -1);
        if (__all(ok)) break;
        __builtin_amdgcn_s_sleep(1);
      }
      *(f16x8*)&hs[tid * 8] = s0v;
      *(f16x8*)&hs[tid * 8 + 4096] = s1v;
    }
    asm volatile("s_waitcnt lgkmcnt(0)\n\ts_barrier" ::: "memory");   // barB
    // recycle slot s-1: this WG re-sentinels its own 512B chunk (dead now:
    // slot s valid => every WG of the group finished staging slot s-1)
    if (s > 0 && wid == 7 && lane < 32)
      st16_sc1(&hbuf[((size_t)((s - 1) & 3) * 8 + g) * 8192 + w * 256 + lane * 8],
               sentinel16);
    // gates = h @ w^T : 32 MFMAs over K=1024 (M rows 8-15 duplicate batches 0-7)
    f32x4 a0 = {}, a1 = {}, a2 = {}, a3 = {};
    #pragma unroll
    for (int t = 0; t < 32; t += 4) {
      f16x8 h0 = *(const f16x8*)&hs[(t + 0) * 256 + hr * 32 + lq * 8];
      f16x8 h1 = *(const f16x8*)&hs[(t + 1) * 256 + hr * 32 + lq * 8];
      f16x8 h2 = *(const f16x8*)&hs[(t + 2) * 256 + hr * 32 + lq * 8];
      f16x8 h3 = *(const f16x8*)&hs[(t + 3) * 256 + hr * 32 + lq * 8];
      a0 = __builtin_amdgcn_mfma_f32_16x16x32_f16(h0, wv[t + 0], a0, 0, 0, 0);
      a1 = __builtin_amdgcn_mfma_f32_16x16x32_f16(h1, wv[t + 1], a1, 0, 0, 0);
      a2 = __builtin_amdgcn_mfma_f32_16x16x32_f16(h2, wv[t + 2], a2, 0, 0, 0);
      a3 = __builtin_amdgcn_mfma_f32_16x16x32_f16(h3, wv[t + 3], a3, 0, 0, 0);
    }
    f32x4 accs = (a0 + a1) + (a2 + a3);
    // bounce pre-acts through this wave's LDS slab (same-wave: lgkm wait only)
    if (lq < 2)
      *(f32x4*)&pre[wid][l15][lq * 4] = accs;   // [n=l15][b=lq*4+reg]
    asm volatile("s_waitcnt lgkmcnt(0)" ::: "memory");
    // wave 7: drain the sentinel reset BEFORE barA (ordering proof needs the
    // reset committed before this WG's publish of step s)
    if (wid == 7) asm volatile("s_waitcnt vmcnt(0)" ::: "memory");
    if (lane < 32) {
      const float p0 = pre[wid][eu * 4 + 0][eb] + (float)gxv[0];
      const float p1 = pre[wid][eu * 4 + 1][eb] + (float)gxv[1];
      const float p2 = pre[wid][eu * 4 + 2][eb] + (float)gxv[2];
      const float p3 = pre[wid][eu * 4 + 3][eb] + (float)gxv[3];
      const float ig = fast_sigmoid(p0);
      const float fg = fast_sigmoid(p1);
      const float gg = fast_tanh(p2);
      const float og = fast_sigmoid(p3);
      creg = fg * creg + ig * gg;
      const float h = og * fast_tanh(creg);
      hpub[eb * 32 + wid * 4 + eu] = (f16)h;
      // out store: normal cached, fire-and-forget (barriers are lgkm-only)
      out[((size_t)s * BSZ + g * 8 + eb) * HSZ + w * 32 + wid * 4 + eu] = h;
      if (s == S_LEN - 1) {
        const int b = g * 8 + eb, J = w * 32 + wid * 4 + eu;
        out[hseq + (size_t)b * HSZ + J] = h;                          // h_f
        out[hseq + (size_t)BSZ * HSZ + (size_t)b * HSZ + J] = creg;   // c_f
      }
    }
    asm volatile("s_waitcnt lgkmcnt(0)\n\ts_barrier" ::: "memory");   // barA
    // publish: wave 0 gathers hpub, ONE contiguous fire-and-forget 512B sc1
    // store into slot s+1 (consumers validate the data itself -- no flag)
    if (wid == 0 && s + 1 < S_LEN && lane < 32) {
      f16x8 hv = *(const f16x8*)&hpub[lane * 8];
      st16_sc1(&hbuf[((size_t)((s + 1) & 3) * 8 + g) * 8192 + w * 256 + lane * 8], hv);
    }
  }
}

// ---- launch --------------------------------------------------------------
extern "C" void kernel_launch(void* const* d_in, const int* in_sizes, int n_in,
                              void* d_out, int out_size, void* d_ws, size_t ws_size,
                              hipStream_t stream) {
  const float* x   = (const float*)d_in[0];
  const float* wih = (const float*)d_in[1];
  const float* whh = (const float*)d_in[2];
  const float* bih = (const float*)d_in[3];
  const float* bhh = (const float*)d_in[4];
  float* out = (float*)d_out;
  char* ws = (char*)d_ws;
  f16*   xh    = (f16*)(ws + 0);           // 33,554,432
  f16*   wih_h = (f16*)(ws + 33554432);    //  4,194,304
  f16*   wp    = (f16*)(ws + 37748736);    //  8,388,608
  float* bsum  = (float*)(ws + 46137344);  //     16,384
  f16*   hbuf  = (f16*)(ws + 46153728);    //    524,288  (4 step-slots)
  f16*   gxp   = (f16*)(ws + 46678016);    // 268,435,456
  // total 315,113,472 B

  k_cvt<<<16384, 256, 0, stream>>>(x, xh, (BSZ * S_LEN * ISZ) / 4);
  k_cvt<<<2048, 256, 0, stream>>>(wih, wih_h, (4 * HSZ * ISZ) / 4);
  k_pack_whh<<<4096, 256, 0, stream>>>(whh, wp);
  k_misc<<<256, 256, 0, stream>>>(bih, bhh, bsum, hbuf);
  dim3 g1(32, 256);
  k_gemm_gx<<<g1, 256, 0, stream>>>(xh, wih_h, bsum, gxp);
  void* args[] = { (void*)&wp, (void*)&gxp, (void*)&hbuf, (void*)&out };
  hipLaunchCooperativeKernel((void*)k_lstm, dim3(256), dim3(512), args, 0, stream);
}